// Round 7
// baseline (321.543 us; speedup 1.0000x reference)
//
#include <hip/hip_runtime.h>
#include <math.h>

// Problem constants (fixed by the reference): N=8, B=4096, D=1024.
#define NN 8
#define BB 4096
#define DD 1024
#define CHUNK 256                // elements per chunk = 64 lanes x 4 floats
#define NCHUNK (BB * 4)          // 16384 chunks
#define NBLK 1280                // 5 persistent single-wave blocks per CU
#define LOG_2PI 1.8378770664093453f

// R7: persistent waves + double-buffered LDS DMA pipeline.
// Each wave continuously has 16-32 DMAs outstanding (no burst-drain-die):
//   stage(k+1 -> bufB); waitvm(16)  [k's DMAs + old stores drained];
//   compute(k from bufA); store; swap.
// DMA issue order rotated by blockIdx&7 to de-phase the 16 plane-streams
// across concurrent waves (free: full-batch waits don't care about order).

#define GLOAD_LDS16(g, l)                                                  \
    __builtin_amdgcn_global_load_lds(                                      \
        (const __attribute__((address_space(1))) unsigned int*)(g),        \
        (__attribute__((address_space(3))) unsigned int*)(l), 16, 0, 0)

#define WAITVM(imm) asm volatile("s_waitcnt vmcnt(" #imm ")" ::: "memory")

__global__ __launch_bounds__(64) void mpc_kernel(
    const float* __restrict__ means,
    const float* __restrict__ logsig,
    float* __restrict__ out_mean,
    float* __restrict__ out_logvar,
    float* __restrict__ out_logz)
{
    __shared__ float smem[2][16 * CHUNK];   // 2 x 16 KB double buffer

    const int lane = threadIdx.x;            // 0..63
    const int rot  = blockIdx.x & 7;
    const size_t plane = (size_t)BB * DD;

    // ---- stage: 16 DMAs for chunk ch into buffer s ----
    auto stage = [&](int ch, int s) {
        const size_t base = (size_t)(ch >> 2) * DD
                          + (size_t)(ch & 3) * CHUNK + (size_t)lane * 4;
#pragma unroll
        for (int i = 0; i < NN; ++i) {
            const int n = (i + rot) & 7;     // de-phased plane order
            GLOAD_LDS16(means  + (size_t)n * plane + base,
                        &smem[s][(2 * n + 0) * CHUNK]);
            GLOAD_LDS16(logsig + (size_t)n * plane + base,
                        &smem[s][(2 * n + 1) * CHUNK]);
        }
    };

    // ---- compute chunk ch from buffer s; 2 stores + 1 atomic at end ----
    auto work = [&](int ch, int s) {
        const int b = ch >> 2;
        const size_t base = (size_t)b * DD
                          + (size_t)(ch & 3) * CHUNK + (size_t)lane * 4;
        const float* buf = smem[s];

        float m1[4], v1[4], iv1[4];
        {
            float4 mm = *(const float4*)&buf[0 * CHUNK + lane * 4];
            float4 ll = *(const float4*)&buf[1 * CHUNK + lane * 4];
            float m[4] = {mm.x, mm.y, mm.z, mm.w};
            float l[4] = {ll.x, ll.y, ll.z, ll.w};
#pragma unroll
            for (int j = 0; j < 4; ++j) {
                m1[j]  = m[j];
                v1[j]  = __expf(l[j]);
                iv1[j] = __expf(-l[j]);
            }
        }
        float z = 0.0f;
#pragma unroll
        for (int n = 1; n < NN; ++n) {
            float4 mm = *(const float4*)&buf[(2 * n + 0) * CHUNK + lane * 4];
            float4 ll = *(const float4*)&buf[(2 * n + 1) * CHUNK + lane * 4];
            float m2[4] = {mm.x, mm.y, mm.z, mm.w};
            float l2[4] = {ll.x, ll.y, ll.z, ll.w};
#pragma unroll
            for (int j = 0; j < 4; ++j) {
                float v2  = __expf(l2[j]);
                float iv2 = __expf(-l2[j]);
                float s2  = v1[j] + v2 + 1e-6f;
                float diff = m1[j] - m2[j];
                z += diff * diff * __builtin_amdgcn_rcpf(s2) + __logf(s2);
                float iv_new = iv1[j] + iv2;
                float cvar   = __builtin_amdgcn_rcpf(iv_new);
                m1[j]  = cvar * (m1[j] * iv1[j] + m2[j] * iv2);
                v1[j]  = cvar;
                iv1[j] = iv_new;
            }
        }
        float4 om = make_float4(m1[0], m1[1], m1[2], m1[3]);
        float4 ol = make_float4(__logf(v1[0]), __logf(v1[1]),
                                __logf(v1[2]), __logf(v1[3]));
        *(float4*)(out_mean + base)   = om;
        *(float4*)(out_logvar + base) = ol;
#pragma unroll
        for (int o = 32; o > 0; o >>= 1)
            z += __shfl_down(z, o, 64);
        if (lane == 0) {
            float partial = -0.5f * z
                          - 0.125f * (float)((NN - 1) * DD) * LOG_2PI;
            atomicAdd(out_logz + b, partial);
        }
    };

    // ---- persistent pipelined loop ----
    int ch = blockIdx.x;
    int s  = 0;
    stage(ch, 0);
    while (true) {
        const int nxt = ch + NBLK;
        if (nxt < NCHUNK) {
            stage(nxt, s ^ 1);
            WAITVM(16);      // cur DMAs (+old stores) drained; next 16 fly
            work(ch, s);
            ch = nxt;
            s ^= 1;
        } else {
            WAITVM(3);       // oldest 16 (cur DMAs) drained; stores may fly
            work(ch, s);
            break;
        }
    }
}

extern "C" void kernel_launch(void* const* d_in, const int* in_sizes, int n_in,
                              void* d_out, int out_size, void* d_ws, size_t ws_size,
                              hipStream_t stream) {
    const float* means  = (const float*)d_in[0];
    const float* logsig = (const float*)d_in[1];
    float* out = (float*)d_out;
    float* out_mean   = out;
    float* out_logvar = out + (size_t)BB * DD;
    float* out_logz   = out + 2 * (size_t)BB * DD;
    hipMemsetAsync(out_logz, 0, BB * sizeof(float), stream);
    mpc_kernel<<<NBLK, 64, 0, stream>>>(means, logsig, out_mean, out_logvar, out_logz);
}